// Round 3
// baseline (182.992 us; speedup 1.0000x reference)
//
#include <hip/hip_runtime.h>
#include <hip/hip_bf16.h>
#include <stdint.h>

#define N_NODES 8192
#define N_EDGES 262144
#define IN_F 512
#define HID 512
#define OUT_F 256
#define CAP 128   // raw append capacity per node; Poisson(32) max ~70, P(>128)~0

typedef __attribute__((ext_vector_type(8))) short short8;
typedef __attribute__((ext_vector_type(4))) float f32x4;

// ---------- bf16 helpers (RNE) ----------
__device__ __forceinline__ float bflo(unsigned int u) {
  union { unsigned int x; float f; } c; c.x = u << 16; return c.f;
}
__device__ __forceinline__ float bfhi(unsigned int u) {
  union { unsigned int x; float f; } c; c.x = u & 0xffff0000u; return c.f;
}
__device__ __forceinline__ float bf1(unsigned short s) {
  union { unsigned int x; float f; } c; c.x = (unsigned int)s << 16; return c.f;
}
__device__ __forceinline__ unsigned short f2bf(float f) {
  union { float f; unsigned int u; } c; c.f = f;
  unsigned int r = c.u + 0x7fffu + ((c.u >> 16) & 1u);
  return (unsigned short)(r >> 16);
}

__device__ __forceinline__ void gload_lds16(const void* g, void* l) {
  __builtin_amdgcn_global_load_lds((const __attribute__((address_space(1))) void*)g,
                                   (__attribute__((address_space(3))) void*)l, 16, 0, 0);
}

// ---------- fused prep: X->bf16 | W1^T->bf16 | W2^T->bf16 | edge append ----------
// sections by block range; one launch replaces 4.
#define NB_CVT  4096   // 8192*512/4 float4 elems / 256
#define NB_W1   1024   // 512*512 / 256
#define NB_W2    512   // 512*256 / 256
#define NB_EDGE 1024   // 262144 / 256
__global__ __launch_bounds__(256) void prep_all(
    const float* __restrict__ x, const float* __restrict__ W1, const float* __restrict__ W2,
    const int* __restrict__ ei,
    unsigned short* __restrict__ Xb, unsigned short* __restrict__ W1t,
    unsigned short* __restrict__ W2t, int* __restrict__ cnt, int* __restrict__ adj) {
  const int b = blockIdx.x, tid = threadIdx.x;
  if (b < NB_CVT) {
    int idx = b * 256 + tid;
    const float4 v = ((const float4*)x)[idx];
    uint2 o;
    o.x = (unsigned int)f2bf(v.x) | ((unsigned int)f2bf(v.y) << 16);
    o.y = (unsigned int)f2bf(v.z) | ((unsigned int)f2bf(v.w) << 16);
    ((uint2*)Xb)[idx] = o;
  } else if (b < NB_CVT + NB_W1) {
    int idx = (b - NB_CVT) * 256 + tid;          // W1 [512][512] row-major
    int k = idx >> 9, n = idx & 511;
    W1t[n * IN_F + k] = f2bf(W1[idx]);
  } else if (b < NB_CVT + NB_W1 + NB_W2) {
    int idx = (b - NB_CVT - NB_W1) * 256 + tid;  // W2 [512][256]
    int k = idx >> 8, n = idx & 255;
    W2t[n * HID + k] = f2bf(W2[idx]);
  } else {
    int e = (b - NB_CVT - NB_W1 - NB_W2) * 256 + tid;
    int i = ei[e];
    int j = ei[N_EDGES + e];
    int p = atomicAdd(&cnt[i], 1);
    if (p < CAP) adj[i * CAP + p] = j;
  }
}

// ---------- per-node dedup (+ degree -> dis) ----------
__global__ __launch_bounds__(128) void dedup_node(
    int* __restrict__ cnt, int* __restrict__ adj, float* __restrict__ dis) {
  const int i = blockIdx.x, t = threadIdx.x;
  __shared__ int js[CAP];
  __shared__ unsigned char keep[CAP];
  int n0 = cnt[i]; if (n0 > CAP) n0 = CAP;
  if (t < n0) js[t] = adj[i * CAP + t];
  __syncthreads();
  bool k = false;
  if (t < n0) {
    k = true;
    int jt = js[t];
    for (int s = 0; s < t; ++s) if (js[s] == jt) { k = false; break; }
  }
  keep[t] = k;
  __syncthreads();
  if (k) {
    int r = 0;
    for (int s = 0; s < t; ++s) r += keep[s];
    adj[i * CAP + r] = js[t];
  }
  if (t == 0) {
    int nd = 0;
    for (int s = 0; s < n0; ++s) nd += keep[s];
    cnt[i] = nd;
    dis[i] = rsqrtf((float)(nd + 1));  // degree = distinct + self-loop
  }
}

// ---------- bf16 MFMA GEMM: C[M,N] = A[M,K] @ Bt[N,K]^T ----------
template<int BM, int BN>
__global__ __launch_bounds__(256) void gemm_bt(
    const unsigned short* __restrict__ A, const unsigned short* __restrict__ Bt,
    unsigned short* __restrict__ C, int M, int N, int K) {
  constexpr int MR = BM / 32, NR = BN / 32;
  __shared__ __align__(16) unsigned short As[BM * 64];
  __shared__ __align__(16) unsigned short Bs[BN * 64];
  const int tid = threadIdx.x;
  const long row0 = (long)blockIdx.x * BM;
  const long col0 = (long)blockIdx.y * BN;
  const int lane = tid & 63;
  const int wid = tid >> 6;
  const int ln15 = lane & 15, hi = lane >> 4;
  const int wr = (wid >> 1) * (BM / 2), wc = (wid & 1) * (BN / 2);
  const int sr = tid >> 3;
  const int sk = (tid & 7) * 8;
  f32x4 acc[MR][NR] = {};

  for (int k0 = 0; k0 < K; k0 += 64) {
#pragma unroll
    for (int c = 0; c < MR; ++c)
      gload_lds16(A  + (row0 + c * 32 + sr) * (long)K + k0 + sk, &As[(c * 256 + tid) * 8]);
#pragma unroll
    for (int c = 0; c < NR; ++c)
      gload_lds16(Bt + (col0 + c * 32 + sr) * (long)K + k0 + sk, &Bs[(c * 256 + tid) * 8]);
    __syncthreads();
#pragma unroll
    for (int kk = 0; kk < 64; kk += 32) {
      short8 a[MR], b[NR];
#pragma unroll
      for (int m = 0; m < MR; ++m)
        a[m] = *(const short8*)&As[(wr + m * 16 + ln15) * 64 + kk + hi * 8];
#pragma unroll
      for (int n = 0; n < NR; ++n)
        b[n] = *(const short8*)&Bs[(wc + n * 16 + ln15) * 64 + kk + hi * 8];
#pragma unroll
      for (int m = 0; m < MR; ++m)
#pragma unroll
        for (int n = 0; n < NR; ++n)
          acc[m][n] = __builtin_amdgcn_mfma_f32_16x16x32_bf16(a[m], b[n], acc[m][n], 0, 0, 0);
    }
    __syncthreads();
  }
#pragma unroll
  for (int m = 0; m < MR; ++m)
#pragma unroll
    for (int n = 0; n < NR; ++n)
#pragma unroll
      for (int r = 0; r < 4; ++r) {
        long row = row0 + wr + m * 16 + hi * 4 + r;
        long col = col0 + wc + n * 16 + ln15;
        C[row * N + col] = f2bf(acc[m][n][r]);
      }
}

// ---------- layer-1 aggregation, column-half passes (4MB working set each) ----------
// out_i = di*(sum_j dj*T_j + di*T_i) + b, relu. blockIdx.y = column half.
__global__ __launch_bounds__(256) void aggregate_relu(
    const unsigned short* __restrict__ T, const int* __restrict__ cnt,
    const int* __restrict__ adj, const float* __restrict__ dis,
    const float* __restrict__ bias, unsigned short* __restrict__ H) {
  const int i = blockIdx.x;
  const int c0 = blockIdx.y * 256;        // feature base of this half
  const int tid = threadIdx.x;
  const int lane = tid & 63, w = tid >> 6;
  __shared__ int js[CAP];
  __shared__ float ws[CAP];
  __shared__ float part[4][256];
  int n = cnt[i];
  if (tid < n) { int j = adj[i * CAP + tid]; js[tid] = j; ws[tid] = dis[j]; }
  __syncthreads();
  float a[4] = {};
  for (int e = w; e < n; e += 4) {
    const uint2 v = *(const uint2*)&T[(long)js[e] * 512 + c0 + lane * 4];
    float wj = ws[e];
    a[0] += wj * bflo(v.x); a[1] += wj * bfhi(v.x);
    a[2] += wj * bflo(v.y); a[3] += wj * bfhi(v.y);
  }
  *(float4*)&part[w][lane * 4] = make_float4(a[0], a[1], a[2], a[3]);
  __syncthreads();
  const float di = dis[i];
  float self = di * bf1(T[(long)i * 512 + c0 + tid]);
  float s = part[0][tid] + part[1][tid] + part[2][tid] + part[3][tid] + self;
  float h = fmaxf(di * s + bias[c0 + tid], 0.f);
  H[(long)i * 512 + c0 + tid] = f2bf(h);
}

// ---------- layer-2 aggregation (T2 = 4MB, single pass) ----------
__global__ __launch_bounds__(256) void aggregate_out(
    const unsigned short* __restrict__ T, const int* __restrict__ cnt,
    const int* __restrict__ adj, const float* __restrict__ dis,
    const float* __restrict__ bias, float* __restrict__ out) {
  const int i = blockIdx.x;
  const int tid = threadIdx.x;
  const int lane = tid & 63, w = tid >> 6;
  __shared__ int js[CAP];
  __shared__ float ws[CAP];
  __shared__ float part[4][256];
  int n = cnt[i];
  if (tid < n) { int j = adj[i * CAP + tid]; js[tid] = j; ws[tid] = dis[j]; }
  __syncthreads();
  float a[4] = {};
  for (int e = w; e < n; e += 4) {
    const uint2 v = *(const uint2*)&T[(long)js[e] * 256 + lane * 4];
    float wj = ws[e];
    a[0] += wj * bflo(v.x); a[1] += wj * bfhi(v.x);
    a[2] += wj * bflo(v.y); a[3] += wj * bfhi(v.y);
  }
  *(float4*)&part[w][lane * 4] = make_float4(a[0], a[1], a[2], a[3]);
  __syncthreads();
  const float di = dis[i];
  float self = di * bf1(T[(long)i * 256 + tid]);
  float s = part[0][tid] + part[1][tid] + part[2][tid] + part[3][tid] + self;
  out[(long)i * 256 + tid] = di * s + bias[tid];
}

extern "C" void kernel_launch(void* const* d_in, const int* in_sizes, int n_in,
                              void* d_out, int out_size, void* d_ws, size_t ws_size,
                              hipStream_t stream) {
  const float* x  = (const float*)d_in[0];
  const int*   ei = (const int*)d_in[1];
  const float* W1 = (const float*)d_in[2];
  const float* b1 = (const float*)d_in[3];
  const float* W2 = (const float*)d_in[4];
  const float* b2 = (const float*)d_in[5];
  float* out = (float*)d_out;

  char* ws = (char*)d_ws;
  int* cnt   = (int*)ws;                     ws += 32768;
  int* adj   = (int*)ws;                     ws += (size_t)N_NODES * CAP * 4;
  float* dis = (float*)ws;                   ws += 32768;
  unsigned short* Xb  = (unsigned short*)ws; ws += (size_t)N_NODES * IN_F * 2;
  unsigned short* W1t = (unsigned short*)ws; ws += (size_t)IN_F * HID * 2;
  unsigned short* W2t = (unsigned short*)ws; ws += (size_t)HID * OUT_F * 2;
  unsigned short* T1  = (unsigned short*)ws; ws += (size_t)N_NODES * HID * 2;
  unsigned short* H   = (unsigned short*)ws; ws += (size_t)N_NODES * HID * 2;
  unsigned short* T2  = (unsigned short*)ws; ws += (size_t)N_NODES * OUT_F * 2;

  hipMemsetAsync(cnt, 0, 32768, stream);  // only 32KB of memset now

  prep_all<<<NB_CVT + NB_W1 + NB_W2 + NB_EDGE, 256, 0, stream>>>(
      x, W1, W2, ei, Xb, W1t, W2t, cnt, adj);
  dedup_node<<<N_NODES, 128, 0, stream>>>(cnt, adj, dis);

  // layer 1: T1 = X @ W1 ; H = relu(Ahat * T1 + b1)
  gemm_bt<128, 64><<<dim3(N_NODES / 128, HID / 64), 256, 0, stream>>>(Xb, W1t, T1, N_NODES, HID, IN_F);
  aggregate_relu<<<dim3(N_NODES, 2), 256, 0, stream>>>(T1, cnt, adj, dis, b1, H);

  // layer 2: T2 = H @ W2 ; out = Ahat * T2 + b2
  gemm_bt<64, 64><<<dim3(N_NODES / 64, OUT_F / 64), 256, 0, stream>>>(H, W2t, T2, N_NODES, OUT_F, HID);
  aggregate_out<<<N_NODES, 256, 0, stream>>>(T2, cnt, adj, dis, b2, out);
}